// Round 11
// baseline (109.020 us; speedup 1.0000x reference)
//
#include <hip/hip_runtime.h>
#include <math.h>

#define T_   2048
#define NB_  64
#define NU_  8
#define NY_  8
#define NH_  256
#define H2_  128
#define CCH  128     // chunks
#define LCH  16      // chunk length

static const float PI_HALF = 1.5707963267948966f;

typedef _Float16 half8  __attribute__((ext_vector_type(8)));
typedef __fp16   fp16x2 __attribute__((ext_vector_type(2)));
typedef float    f32x4  __attribute__((ext_vector_type(4)));

// K-index m = 2h + comp (comp0 = x1 of pair h, comp1 = x2). Conv K-index
// c = tau*8 + u. A_all rows: 0..127 = G' (Y_local), 128..383 = E' (endpoints).
// ws layout (bytes):
#define OFF_AALL 0          // f16 [384][128]   96 KB
#define OFF_M    98304      // f16 [128][256]   64 KB
#define OFF_LAML 163840     // float2[128]      1 KB
#define OFF_CBUF 164864     // f32 [128k][64b][256m]  8 MB
#define OFF_INIT 8553472    // u32 [128k][64b][128]   4 MB

// ---------------- kernel 0: operator precompute ----------------
__global__ __launch_bounds__(64) void k_pre(
    const float* __restrict__ lr, const float* __restrict__ li,
    const float* __restrict__ B, const float* __restrict__ mult,
    const float* __restrict__ Wx2y, char* __restrict__ ws)
{
    const int bi = blockIdx.x;
    const int j  = threadIdx.x;

    if (bi < 128) {
        // ---- G' row R: cols 2j, 2j+1 ----
        __shared__ float2 rotS[128*16];   // [h][e] (re_e, im_e)
        __shared__ float2 BsS[128*8];     // [h][u] (Bs1, Bs2)
        const int R = bi, dlt = R >> 3, y = R & 7;
        #pragma unroll
        for (int i = 0; i < 32; i++) {
            const int idx = j*32 + i, h = idx >> 4, e = idx & 15;
            float a   = fabsf(lr[h]);
            float r   = expf(-(float)e * a);
            float ang = (float)e * PI_HALF * li[h];
            rotS[h*16 + e] = make_float2(r*cosf(ang), r*sinf(ang));
        }
        #pragma unroll
        for (int i = 0; i < 16; i++) {
            const int idx = j*16 + i, h = idx >> 3, u = idx & 7;
            BsS[h*8 + u] = make_float2(B[h*NU_ + u]       * expf(mult[h]),
                                       B[(h+H2_)*NU_ + u] * expf(mult[h+H2_]));
        }
        __syncthreads();

        const int tau = j >> 2, u0 = (2*j) & 7;
        uint32_t out = 0;
        if (tau <= dlt) {
            const int e = dlt - tau;
            float g0 = 0.f, g1 = 0.f;
            for (int h = 0; h < 128; h++) {
                float2 rot = rotS[h*16 + e];
                float2 b0  = BsS[h*8 + u0];
                float2 b1  = BsS[h*8 + u0 + 1];
                float W1 = Wx2y[y*NH_ + h], W2 = Wx2y[y*NH_ + H2_ + h];
                g0 += W1*fmaf(rot.x, b0.x, -rot.y*b0.y)
                    + W2*fmaf(rot.y, b0.x,  rot.x*b0.y);
                g1 += W1*fmaf(rot.x, b1.x, -rot.y*b1.y)
                    + W2*fmaf(rot.y, b1.x,  rot.x*b1.y);
            }
            union { fp16x2 h2; uint32_t u; } pk;
            pk.h2 = __builtin_amdgcn_cvt_pkrtz(g0, g1);
            out = pk.u;
        }
        ((uint32_t*)(ws + OFF_AALL))[R*64 + j] = out;
    } else if (bi < 384) {
        // ---- E' row m = bi-128 -> A_all row 128+m ----
        const int m = bi - 128, h = m >> 1, comp = m & 1;
        const int tau = j >> 2, u0 = (2*j) & 7;
        const int e = (LCH-1) - tau;
        float a   = fabsf(lr[h]);
        float r   = expf(-(float)e * a);
        float ang = (float)e * PI_HALF * li[h];
        float re = r*cosf(ang), im = r*sinf(ang);
        float s1 = expf(mult[h]), s2 = expf(mult[h+H2_]);
        float B1a = B[h*NU_+u0]*s1,       B2a = B[(h+H2_)*NU_+u0]*s2;
        float B1b = B[h*NU_+u0+1]*s1,     B2b = B[(h+H2_)*NU_+u0+1]*s2;
        float v0 = comp ? fmaf(im,B1a, re*B2a) : fmaf(re,B1a, -im*B2a);
        float v1 = comp ? fmaf(im,B1b, re*B2b) : fmaf(re,B1b, -im*B2b);
        union { fp16x2 h2; uint32_t u; } pk;
        pk.h2 = __builtin_amdgcn_cvt_pkrtz(v0, v1);
        ((uint32_t*)(ws + OFF_AALL))[(128 + m)*64 + j] = pk.u;
    } else if (bi < 512) {
        // ---- M row R = bi-384 (e = delta+1) ----
        uint32_t* M32 = (uint32_t*)(ws + OFF_M);
        const int R = bi - 384, dlt = R >> 3, y = R & 7;
        const float e = (float)(dlt + 1);
        #pragma unroll
        for (int hh = 0; hh < 2; hh++) {
            const int h = j + hh*64;
            float r  = expf(-e * fabsf(lr[h]));
            float an = e * PI_HALF * li[h];
            float c = r*cosf(an), sn = r*sinf(an);
            float W1 = Wx2y[y*NH_ + h];
            float W2 = Wx2y[y*NH_ + h + H2_];
            float Mre = fmaf(W1, c,  W2 * sn);
            float Mim = fmaf(W2, c, -W1 * sn);
            union { fp16x2 h2; uint32_t u32; } pk;
            pk.h2 = __builtin_amdgcn_cvt_pkrtz(Mre, Mim);
            M32[R*128 + hh*64 + j] = pk.u32;
        }
    } else {
        // ---- lamL = Lambda^16 ----
        float2* lamL = (float2*)(ws + OFF_LAML);
        #pragma unroll
        for (int hh = 0; hh < 2; hh++) {
            const int h = j + hh*64;
            float a   = fabsf(lr[h]);
            float rL  = expf(-(float)LCH * a);
            float thL = (float)LCH * PI_HALF * li[h];
            lamL[h] = make_float2(rL*cosf(thL), rL*sinf(thL));
        }
    }
}

// ---------------- kernel 1: per-chunk conv GEMM [384 x 64, K=128] -----------
// grid = 3 rowgroups x 128 chunks; 256 threads = 4 waves; 2 rowtiles/wave.
__global__ __launch_bounds__(256) void k_conv(
    const float* __restrict__ U, const float* __restrict__ bx2y,
    char* __restrict__ ws, float* __restrict__ Y)
{
    const int bi = blockIdx.x;
    const int k  = bi & 127, rg = bi >> 7;
    const int tid = threadIdx.x;
    const int w = tid >> 6, l = tid & 63;
    const int lane16 = l & 15, kg = l >> 4;

    __shared__ _Float16 bS[64*136];    // [b-row][128 k-halves], stride 136
    uint32_t* bS32 = (uint32_t*)bS;

    // stage chunk of U (16t x 64b x 8u f32 = 32 KB) -> f16 bS[b][tau*8+u]
    const float* Uk = U + (size_t)k * (LCH*NB_*NU_);
    #pragma unroll
    for (int i = 0; i < 8; i++) {
        const int flat = i*1024 + tid*4;
        float4 v = *(const float4*)(Uk + flat);
        const int tau = flat >> 9, b = (flat >> 3) & 63, u0 = flat & 7;
        union { fp16x2 h2; uint32_t u; } pA, pB;
        pA.h2 = __builtin_amdgcn_cvt_pkrtz(v.x, v.y);
        pB.h2 = __builtin_amdgcn_cvt_pkrtz(v.z, v.w);
        const int d = b*68 + tau*4 + (u0 >> 1);
        bS32[d] = pA.u; bS32[d+1] = pB.u;
    }
    __syncthreads();

    // B fragments (cached across rowtiles): lane reads bS[n=b][8 k's]
    half8 bf[4][4];
    #pragma unroll
    for (int ct = 0; ct < 4; ct++)
        #pragma unroll
        for (int q = 0; q < 4; q++)
            bf[ct][q] = *(const half8*)(bS + (ct*16 + lane16)*136 + q*32 + kg*8);

    const _Float16* Aall = (const _Float16*)(ws + OFF_AALL);
    float* cbuf = (float*)(ws + OFF_CBUF) + (size_t)k*16384;
    const float4 bias4 = *(const float4*)(bx2y + (kg & 1)*4);

    #pragma unroll
    for (int rt = 0; rt < 2; rt++) {
        const int R0 = rg*128 + w*32 + rt*16;
        half8 af[4];
        #pragma unroll
        for (int q = 0; q < 4; q++)
            af[q] = *(const half8*)(Aall + (size_t)(R0 + lane16)*128 + q*32 + kg*8);

        f32x4 acc[4] = {{0,0,0,0},{0,0,0,0},{0,0,0,0},{0,0,0,0}};
        #pragma unroll
        for (int q = 0; q < 4; q++)
            #pragma unroll
            for (int ct = 0; ct < 4; ct++)
                acc[ct] = __builtin_amdgcn_mfma_f32_16x16x32_f16(
                              af[q], bf[ct][q], acc[ct], 0, 0, 0);

        if (R0 < 128) {
            // Y_local rows: delta = R>>3, y = R&7
            const int t  = k*LCH + (R0 >> 3) + (kg >> 1);
            const int y0 = (kg & 1)*4;
            #pragma unroll
            for (int ct = 0; ct < 4; ct++) {
                const int b = ct*16 + lane16;
                float4 o;
                o.x = acc[ct][0] + bias4.x;
                o.y = acc[ct][1] + bias4.y;
                o.z = acc[ct][2] + bias4.z;
                o.w = acc[ct][3] + bias4.w;
                *(float4*)(Y + ((size_t)t*NB_ + b)*NY_ + y0) = o;
            }
        } else {
            // endpoint rows: m = R-128
            const int m0 = (R0 - 128) + kg*4;
            #pragma unroll
            for (int ct = 0; ct < 4; ct++) {
                const int b = ct*16 + lane16;
                *(float4*)(cbuf + b*256 + m0) =
                    make_float4(acc[ct][0], acc[ct][1], acc[ct][2], acc[ct][3]);
            }
        }
    }
}

// ---------------- kernel 2: chunk prefix -> f16 inits ----------------
__global__ __launch_bounds__(64) void k_prefix(
    const float* __restrict__ y0, const float* __restrict__ Wy2x,
    const float* __restrict__ by2x, const char* __restrict__ ws,
    uint32_t* __restrict__ initT)
{
    const int g = blockIdx.x*64 + threadIdx.x;   // 0..8191
    const int b = g >> 7;
    const int h = g & 127;

    float x1 = by2x[h], x2 = by2x[h+H2_];
    #pragma unroll
    for (int y = 0; y < NY_; y++) {
        float yy = y0[b*NY_ + y];
        x1 = fmaf(yy, Wy2x[h*NY_ + y],        x1);
        x2 = fmaf(yy, Wy2x[(h+H2_)*NY_ + y],  x2);
    }

    const float2 lL = ((const float2*)(ws + OFF_LAML))[h];
    const float reL = lL.x, imL = lL.y;
    const float* cbuf = (const float*)(ws + OFF_CBUF);

    #pragma unroll 8
    for (int k = 0; k < CCH; k++) {
        float2 c = *(const float2*)(cbuf + (size_t)k*16384 + b*256 + 2*h);
        union { fp16x2 hh; uint32_t u32; } pk;
        pk.hh = __builtin_amdgcn_cvt_pkrtz(x1, x2);
        initT[(size_t)k*8192 + b*128 + h] = pk.u32;
        float n1 = fmaf(reL, x1, fmaf(-imL, x2, c.x));
        float n2 = fmaf(imL, x1, fmaf( reL, x2, c.y));
        x1 = n1; x2 = n2;
    }
}

// ---------------- kernel 3: correction GEMM, Y += M @ init_k -----------------
// 256 blocks = (k, b-half); 256 threads = 4 waves; 2 rowtiles/wave.
__global__ __launch_bounds__(256) void k_corr(
    const _Float16* __restrict__ M, const uint32_t* __restrict__ initT,
    float* __restrict__ Y)
{
    const int bi   = blockIdx.x;
    const int k    = bi >> 1;
    const int half = bi & 1;
    const int tid  = threadIdx.x;
    const int w    = tid >> 6, l = tid & 63;
    const int lane16 = l & 15, kg = l >> 4;

    __shared__ _Float16 bS[32*264];
    {
        uint32_t* bS32 = (uint32_t*)bS;
        const int r = tid >> 3, seg = tid & 7;
        const uint32_t* src = initT + (size_t)k*8192 + (half*32 + r)*128 + seg*16;
        uint32_t* dst = bS32 + r*132 + seg*16;
        ((uint4*)dst)[0] = ((const uint4*)src)[0];
        ((uint4*)dst)[1] = ((const uint4*)src)[1];
        ((uint4*)dst)[2] = ((const uint4*)src)[2];
        ((uint4*)dst)[3] = ((const uint4*)src)[3];
    }
    __syncthreads();

    #pragma unroll
    for (int rt = 0; rt < 2; rt++) {
        const int R0 = (w*2 + rt)*16;
        half8 af[8];
        #pragma unroll
        for (int q = 0; q < 8; q++)
            af[q] = *(const half8*)(M + (size_t)(R0 + lane16)*256 + q*32 + kg*8);

        f32x4 acc0 = {0,0,0,0}, acc1 = {0,0,0,0};
        #pragma unroll
        for (int q = 0; q < 8; q++) {
            const half8* b0 = (const half8*)(bS + ( 0 + lane16)*264 + q*32 + kg*8);
            const half8* b1 = (const half8*)(bS + (16 + lane16)*264 + q*32 + kg*8);
            acc0 = __builtin_amdgcn_mfma_f32_16x16x32_f16(af[q], *b0, acc0, 0, 0, 0);
            acc1 = __builtin_amdgcn_mfma_f32_16x16x32_f16(af[q], *b1, acc1, 0, 0, 0);
        }

        const int t  = k*LCH + (R0 >> 3) + (kg >> 1);
        const int y0 = (kg & 1)*4;
        float4* yp0 = (float4*)(Y + ((size_t)t*NB_ + half*32 +  0 + lane16)*NY_ + y0);
        float4* yp1 = (float4*)(Y + ((size_t)t*NB_ + half*32 + 16 + lane16)*NY_ + y0);
        float4 o0 = *yp0, o1 = *yp1;
        o0.x += acc0[0]; o0.y += acc0[1]; o0.z += acc0[2]; o0.w += acc0[3];
        o1.x += acc1[0]; o1.y += acc1[1]; o1.z += acc1[2]; o1.w += acc1[3];
        *yp0 = o0; *yp1 = o1;
    }
}

extern "C" void kernel_launch(void* const* d_in, const int* in_sizes, int n_in,
                              void* d_out, int out_size, void* d_ws, size_t ws_size,
                              hipStream_t stream) {
    const float* y0   = (const float*)d_in[0];
    const float* U    = (const float*)d_in[1];
    const float* lr   = (const float*)d_in[2];
    const float* li   = (const float*)d_in[3];
    const float* B    = (const float*)d_in[4];
    const float* mult = (const float*)d_in[5];
    const float* Wy2x = (const float*)d_in[6];
    const float* by2x = (const float*)d_in[7];
    const float* Wx2y = (const float*)d_in[8];
    const float* bx2y = (const float*)d_in[9];
    float* Y = (float*)d_out;

    char*     ws    = (char*)d_ws;
    uint32_t* initT = (uint32_t*)(ws + OFF_INIT);
    const _Float16* Mf = (const _Float16*)(ws + OFF_M);

    k_pre   <<<513, 64, 0, stream>>>(lr, li, B, mult, Wx2y, ws);
    k_conv  <<<3*CCH, 256, 0, stream>>>(U, bx2y, ws, Y);
    k_prefix<<<(NB_*H2_)/64, 64, 0, stream>>>(y0, Wy2x, by2x, ws, initT);
    k_corr  <<<CCH*2, 256, 0, stream>>>(Mf, initT, Y);
}

// Round 12
// 103.163 us; speedup vs baseline: 1.0568x; 1.0568x over previous
//
#include <hip/hip_runtime.h>
#include <math.h>

#define T_   2048
#define NB_  64
#define NU_  8
#define NY_  8
#define NH_  256
#define H2_  128
#define CCH  64      // number of chunks
#define LCH  32      // chunk length = T_/CCH

static const float PI_HALF = 1.5707963267948966f;

typedef _Float16 half8  __attribute__((ext_vector_type(8)));
typedef __fp16   fp16x2 __attribute__((ext_vector_type(2)));
typedef float    f32x4  __attribute__((ext_vector_type(4)));

// ws layout (bytes):
//   lamP  f32x4[128] (re,im,-im,re)      @ 0        2 KB
//   lamL  float2[128] (Lambda^L)         @ 2048     1 KB
//   Bs    f32[128][16] (B1s|B2s rows)    @ 4096     8 KB
//   Wm16  u32[8][128] pk(W[y][h],W[y][h+128]) @ 12288  4 KB
//   M     u32[256][128]                  @ 16384    128 KB
//   c_buf f32[k][b][pair][2]             @ 147456   4 MB
//   initT u32[k][b][128]                 @ 4341760  2 MB
#define OFF_LAMP  0
#define OFF_LAML  2048
#define OFF_BS    4096
#define OFF_WM16  12288
#define OFF_M     16384
#define OFF_CBUF  147456
#define OFF_INIT  4341760

// ---------------- kernel 0: coefficient precompute ----------------
__global__ __launch_bounds__(64) void k_pre(
    const float* __restrict__ lr, const float* __restrict__ li,
    const float* __restrict__ B, const float* __restrict__ mult,
    const float* __restrict__ Wx2y, char* __restrict__ ws)
{
    const int bi = blockIdx.x;
    const int j  = threadIdx.x;

    if (bi < 256) {
        // M[R=dlt*8+y][m]
        uint32_t* M32 = (uint32_t*)(ws + OFF_M);
        const int dlt = bi >> 3, y = bi & 7;
        const float e = (float)(dlt + 1);
        #pragma unroll
        for (int hh = 0; hh < 2; hh++) {
            const int h = j + hh*64;
            float r  = expf(-e * fabsf(lr[h]));
            float an = e * PI_HALF * li[h];
            float c = r * cosf(an), sn = r * sinf(an);
            float W1 = Wx2y[y*NH_ + h];
            float W2 = Wx2y[y*NH_ + h + H2_];
            float Mre = fmaf(W1, c,  W2 * sn);
            float Mim = fmaf(W2, c, -W1 * sn);
            union { fp16x2 h2; uint32_t u32; } pk;
            pk.h2 = __builtin_amdgcn_cvt_pkrtz(Mre, Mim);
            M32[bi*128 + hh*64 + j] = pk.u32;
        }
    } else if (bi == 256) {
        // lamP + lamL for pairs j, j+64
        float4* lamP = (float4*)(ws + OFF_LAMP);
        float2* lamL = (float2*)(ws + OFF_LAML);
        #pragma unroll
        for (int hh = 0; hh < 2; hh++) {
            const int h = j + hh*64;
            float a  = fabsf(lr[h]);
            float r  = expf(-a);
            float th = PI_HALF * li[h];
            float re = r * cosf(th), im = r * sinf(th);
            lamP[h] = make_float4(re, im, -im, re);
            float rL  = expf(-(float)LCH * a);
            float thL = (float)LCH * PI_HALF * li[h];
            lamL[h] = make_float2(rL * cosf(thL), rL * sinf(thL));
        }
    } else if (bi == 257) {
        // Bs[h][0..7] = B[h]*exp(mult[h]); Bs[h][8..15] = B[h+128]*exp(mult[h+128])
        float* Bs = (float*)(ws + OFF_BS);
        #pragma unroll
        for (int hh = 0; hh < 2; hh++) {
            const int h = j + hh*64;
            float s1 = expf(mult[h]), s2 = expf(mult[h+H2_]);
            #pragma unroll
            for (int i = 0; i < NU_; i++) {
                Bs[h*16 + i]     = B[h*NU_ + i]        * s1;
                Bs[h*16 + 8 + i] = B[(h+H2_)*NU_ + i]  * s2;
            }
        }
    } else {
        // Wm16[y][h] = pk(Wx2y[y][h], Wx2y[y][h+128])
        uint32_t* Wm = (uint32_t*)(ws + OFF_WM16);
        #pragma unroll
        for (int y = 0; y < NY_; y++) {
            #pragma unroll
            for (int hh = 0; hh < 2; hh++) {
                const int h = j + hh*64;
                union { fp16x2 h2; uint32_t u32; } pk;
                pk.h2 = __builtin_amdgcn_cvt_pkrtz(Wx2y[y*NH_ + h],
                                                   Wx2y[y*NH_ + h + H2_]);
                Wm[y*128 + h] = pk.u32;
            }
        }
    }
}

// ---------------- kernel 1: scan from zero + K-split MFMA projection ---------
// 128 threads = 2 waves. Thread tid owns pair h = tid (chans h, h+128).
__global__ __launch_bounds__(128) void k_scanproj(
    const float* __restrict__ U, const float* __restrict__ bx2y,
    const char* __restrict__ ws, float* __restrict__ c_buf,
    float* __restrict__ Y)
{
    const int k   = blockIdx.x >> 6;
    const int b   = blockIdx.x & 63;
    const int tid = threadIdx.x;
    const int h   = tid;
    const int w   = tid >> 6;
    const int l   = tid & 63;
    const int row = l & 15;
    const int kg  = (l >> 4) & 3;

    // packed coefficient loads (L2-hot, no transcendentals)
    const float4 lam = ((const float4*)(ws + OFF_LAMP))[h];   // re, im, -im, re
    float B1[NU_], B2[NU_];
    {
        const float4* bsp = (const float4*)(ws + OFF_BS) + h*4;
        float4 a0 = bsp[0], a1 = bsp[1], a2 = bsp[2], a3 = bsp[3];
        B1[0]=a0.x; B1[1]=a0.y; B1[2]=a0.z; B1[3]=a0.w;
        B1[4]=a1.x; B1[5]=a1.y; B1[6]=a1.z; B1[7]=a1.w;
        B2[0]=a2.x; B2[1]=a2.y; B2[2]=a2.z; B2[3]=a2.w;
        B2[4]=a3.x; B2[5]=a3.y; B2[6]=a3.z; B2[7]=a3.w;
    }
    half8 wf[4];
    {
        const uint32_t* Wm = (const uint32_t*)(ws + OFF_WM16);
        #pragma unroll
        for (int q2 = 0; q2 < 4; q2++) {
            const int q = 4*w + q2;
            union { uint4 u4; half8 h8; } fu;
            if (row < 8) fu.u4 = *(const uint4*)(Wm + row*128 + q*16 + kg*4);
            else         fu.u4 = make_uint4(0,0,0,0);
            wf[q2] = fu.h8;
        }
    }
    const float bias = bx2y[tid & 7];

    __shared__ float    uS[LCH*NU_];    // 1 KB
    __shared__ _Float16 xS[16*256];     // 8 KB
    __shared__ float    pS[4*132];
    uint32_t* xS32 = (uint32_t*)xS;

    if (tid < 64) {
        ((float4*)uS)[tid] =
            *(const float4*)(U + ((size_t)(k*LCH + (tid>>1))*NB_ + b)*NU_ + (tid&1)*4);
    }
    __syncthreads();

    float x1 = 0.f, x2 = 0.f;
    const int g = h >> 2;

    for (int s = 0; s < 2; s++) {
        #pragma unroll 4
        for (int t16 = 0; t16 < 16; t16++) {
            const int t = s*16 + t16;
            float4 u0 = ((const float4*)uS)[2*t+0];
            float4 u1 = ((const float4*)uS)[2*t+1];
            float u[NU_] = {u0.x,u0.y,u0.z,u0.w,u1.x,u1.y,u1.z,u1.w};
            float bu1=0.f, bu2=0.f;
            #pragma unroll
            for (int i = 0; i < NU_; i++) {
                bu1 = fmaf(u[i], B1[i], bu1);
                bu2 = fmaf(u[i], B2[i], bu2);
            }
            float n1 = fmaf(lam.x, x1, fmaf(lam.z, x2, bu1));
            float n2 = fmaf(lam.y, x1, fmaf(lam.w, x2, bu2));
            x1 = n1; x2 = n2;

            union { fp16x2 h2; uint32_t u32; } pk;
            pk.h2 = __builtin_amdgcn_cvt_pkrtz(x1, x2);
            xS32[t16*128 + ((g ^ t16) & 31)*4 + (h & 3)] = pk.u32;
        }
        __syncthreads();

        f32x4 acc = {0.f,0.f,0.f,0.f};
        #pragma unroll
        for (int q2 = 0; q2 < 4; q2++) {
            const int q = 4*w + q2;
            const int p = ((q << 2) + kg) ^ row;
            const half8* ap = (const half8*)(xS + (row << 8) + (p << 3));
            acc = __builtin_amdgcn_mfma_f32_16x16x32_f16(*ap, wf[q2], acc, 0, 0, 0);
        }
        #pragma unroll
        for (int r = 0; r < 4; r++) pS[r*132 + w*64 + l] = acc[r];
        __syncthreads();

        {
            const int t  = tid >> 3, y = tid & 7;
            const int ls = ((t >> 2) << 4) + y;
            const int rg = t & 3;
            float sum = pS[rg*132 + ls] + pS[rg*132 + 64 + ls];
            Y[((size_t)(k*LCH + s*16 + t)*NB_ + b)*NY_ + y] = sum + bias;
        }
    }

    *(float2*)(c_buf + (size_t)(k*NB_ + b)*(H2_*2) + 2*h) = make_float2(x1, x2);
}

// ---------------- kernel 2: chunk prefix -> f16 transposed inits --------------
__global__ __launch_bounds__(64) void k_prefix(
    const float* __restrict__ y0, const float* __restrict__ Wy2x,
    const float* __restrict__ by2x, const char* __restrict__ ws,
    const float* __restrict__ c_buf, uint32_t* __restrict__ initT)
{
    const int g = blockIdx.x*64 + threadIdx.x;
    const int b = g >> 7;
    const int h = g & 127;

    float x1 = by2x[h], x2 = by2x[h+H2_];
    #pragma unroll
    for (int y = 0; y < NY_; y++) {
        float yy = y0[b*NY_ + y];
        x1 = fmaf(yy, Wy2x[h*NY_ + y],        x1);
        x2 = fmaf(yy, Wy2x[(h+H2_)*NY_ + y],  x2);
    }

    const float2 lL = ((const float2*)(ws + OFF_LAML))[h];
    const float reL = lL.x, imL = lL.y;

    #pragma unroll 8
    for (int k = 0; k < CCH; k++) {
        float2 c = *(const float2*)(c_buf + (size_t)k*16384 + b*256 + 2*h);
        union { fp16x2 hh; uint32_t u32; } pk;
        pk.hh = __builtin_amdgcn_cvt_pkrtz(x1, x2);
        initT[(size_t)k*8192 + b*128 + h] = pk.u32;
        float n1 = fmaf(reL, x1, fmaf(-imL, x2, c.x));
        float n2 = fmaf(imL, x1, fmaf( reL, x2, c.y));
        x1 = n1; x2 = n2;
    }
}

// ---------------- kernel 3: correction GEMM, Y += M @ init_k -----------------
// 512 blocks = (k, b-half, R-tile-group); 256 threads = 4 waves, 1 R-tile/wave.
// bS staging: 256 threads x 16 dwords = full 32 rows x 128 dwords.
__global__ __launch_bounds__(256) void k_corr(
    const _Float16* __restrict__ M, const uint32_t* __restrict__ initT,
    float* __restrict__ Y)
{
    const int bi   = blockIdx.x;
    const int k    = bi >> 3;
    const int half = (bi >> 2) & 1;
    const int rtg  = bi & 3;
    const int tid  = threadIdx.x;
    const int w    = tid >> 6, l = tid & 63;
    const int lane16 = l & 15, kg = l >> 4;

    __shared__ _Float16 bS[32*264];
    {
        uint32_t* bS32 = (uint32_t*)bS;
        const int r = tid >> 3, seg = tid & 7;
        const uint32_t* src = initT + (size_t)k*8192 + (half*32 + r)*128 + seg*16;
        uint32_t* dst = bS32 + r*132 + seg*16;
        ((uint4*)dst)[0] = ((const uint4*)src)[0];
        ((uint4*)dst)[1] = ((const uint4*)src)[1];
        ((uint4*)dst)[2] = ((const uint4*)src)[2];
        ((uint4*)dst)[3] = ((const uint4*)src)[3];
    }
    __syncthreads();

    const int R0 = rtg*64 + w*16;
    half8 af[8];
    #pragma unroll
    for (int q = 0; q < 8; q++)
        af[q] = *(const half8*)(M + (size_t)(R0 + lane16)*256 + q*32 + kg*8);

    f32x4 acc0 = {0.f,0.f,0.f,0.f}, acc1 = {0.f,0.f,0.f,0.f};
    #pragma unroll
    for (int q = 0; q < 8; q++) {
        const half8* b0 = (const half8*)(bS + ( 0 + lane16)*264 + q*32 + kg*8);
        const half8* b1 = (const half8*)(bS + (16 + lane16)*264 + q*32 + kg*8);
        acc0 = __builtin_amdgcn_mfma_f32_16x16x32_f16(af[q], *b0, acc0, 0, 0, 0);
        acc1 = __builtin_amdgcn_mfma_f32_16x16x32_f16(af[q], *b1, acc1, 0, 0, 0);
    }

    const int t  = k*LCH + (R0 >> 3) + (kg >> 1);
    const int y0 = (kg & 1) * 4;
    float4* yp0 = (float4*)(Y + ((size_t)t*NB_ + half*32 +  0 + lane16)*NY_ + y0);
    float4* yp1 = (float4*)(Y + ((size_t)t*NB_ + half*32 + 16 + lane16)*NY_ + y0);
    float4 o0 = *yp0, o1 = *yp1;
    o0.x += acc0[0]; o0.y += acc0[1]; o0.z += acc0[2]; o0.w += acc0[3];
    o1.x += acc1[0]; o1.y += acc1[1]; o1.z += acc1[2]; o1.w += acc1[3];
    *yp0 = o0; *yp1 = o1;
}

extern "C" void kernel_launch(void* const* d_in, const int* in_sizes, int n_in,
                              void* d_out, int out_size, void* d_ws, size_t ws_size,
                              hipStream_t stream) {
    const float* y0   = (const float*)d_in[0];
    const float* U    = (const float*)d_in[1];
    const float* lr   = (const float*)d_in[2];
    const float* li   = (const float*)d_in[3];
    const float* B    = (const float*)d_in[4];
    const float* mult = (const float*)d_in[5];
    const float* Wy2x = (const float*)d_in[6];
    const float* by2x = (const float*)d_in[7];
    const float* Wx2y = (const float*)d_in[8];
    const float* bx2y = (const float*)d_in[9];
    float* Y = (float*)d_out;

    char*     ws    = (char*)d_ws;
    float*    c_buf = (float*)(ws + OFF_CBUF);
    uint32_t* initT = (uint32_t*)(ws + OFF_INIT);
    const _Float16* Mf = (const _Float16*)(ws + OFF_M);

    k_pre     <<<259, 64, 0, stream>>>(lr, li, B, mult, Wx2y, ws);
    k_scanproj<<<CCH*NB_, 128, 0, stream>>>(U, bx2y, ws, c_buf, Y);
    k_prefix  <<<(NB_*H2_)/64, 64, 0, stream>>>(y0, Wy2x, by2x, ws, c_buf, initT);
    k_corr    <<<CCH*8, 256, 0, stream>>>(Mf, initT, Y);
}